// Round 9
// baseline (385.040 us; speedup 1.0000x reference)
//
#include <hip/hip_runtime.h>

#define NN 8192
#define DD 768
#define EE 131072
#define BBg 64
#define LLn 128
#define CCh 384

typedef unsigned short u16;
typedef unsigned char u8;
typedef __attribute__((ext_vector_type(8))) short short8;
typedef __attribute__((ext_vector_type(4))) float f32x4;

__device__ __forceinline__ float b2f(u16 u) {
    union { unsigned int i; float f; } x; x.i = ((unsigned int)u) << 16; return x.f;
}
__device__ __forceinline__ u16 f2b(float f) {
    union { float f; unsigned int i; } x; x.f = f;
    unsigned int r = x.i + 0x7fffu + ((x.i >> 16) & 1u);
    return (u16)(r >> 16);
}
__device__ __forceinline__ void gload16(const void* g, void* l) {
    __builtin_amdgcn_global_load_lds((const __attribute__((address_space(1))) void*)g,
                                     (__attribute__((address_space(3))) void*)l, 16, 0, 0);
}

// ---------------- prep: zero cnt + zero score + f32->bf16 convert (1 dispatch) ----------------
__global__ __launch_bounds__(256) void prep_kernel(const float* __restrict__ in,
                                                   u16* __restrict__ out,
                                                   unsigned int* __restrict__ cnt32,
                                                   float* __restrict__ score) {
    int i = blockIdx.x * 256 + threadIdx.x;   // grid 6144 blocks: i < NN*DD/4
    float4 v = ((const float4*)in)[i];
    ushort4 o; o.x = f2b(v.x); o.y = f2b(v.y); o.z = f2b(v.z); o.w = f2b(v.w);
    ((ushort4*)out)[i] = o;
    if (blockIdx.x < 1024) cnt32[i] = 0;                       // 1 MB cnt
    else if (blockIdx.x < 1056) score[i - 1024 * 256] = 0.f;   // 8192 floats
}

// ---------------- combo: weight transposes (z<11) + edge histogram (z=11) ----------------
struct TP { const float* src; u16* dst; int rowOff; };
struct TP11 { TP a[11]; };

__global__ __launch_bounds__(256) void combo_kernel(TP11 args,
                                                    const int* __restrict__ srcp,
                                                    const int* __restrict__ dstp,
                                                    unsigned int* __restrict__ cnt32) {
    __shared__ float tile[64][65];
    if (blockIdx.z == 11) {
        for (int e = blockIdx.x * 256 + threadIdx.x; e < EE; e += 144 * 256) {
            int d = dstp[e], s = srcp[e];
            int g = d >> 7;
            int idx = (g << 14) + ((d & 127) << 7) + (s & 127);
            atomicAdd(&cnt32[idx >> 2], 1u << ((idx & 3) * 8));
        }
        return;
    }
    TP tp = args.a[blockIdx.z];
    int bx = blockIdx.x % 12, by = blockIdx.x / 12;
    int n0 = bx * 64, k0 = by * 64;
    int t = threadIdx.x;
    int tc = t & 63, tr = t >> 6;
#pragma unroll
    for (int i = 0; i < 16; i++)
        tile[tr + i * 4][tc] = tp.src[(size_t)(tp.rowOff + k0 + tr + i * 4) * DD + n0 + tc];
    __syncthreads();
#pragma unroll
    for (int i = 0; i < 16; i++) {
        int row = tr + i * 4;
        tp.dst[(size_t)(n0 + row) * DD + k0 + tc] = f2b(tile[tc][row]);
    }
}

// ---------------- QKVS GEMM: 256x128 tile, swizzled LDS, global_load_lds w16 ----------------
__global__ __launch_bounds__(256, 2) void gemm256(const u16* __restrict__ A,
                                                  const u16* __restrict__ Wt,
                                                  const float* __restrict__ b0,
                                                  const float* __restrict__ b1,
                                                  const float* __restrict__ b2,
                                                  const float* __restrict__ b3,
                                                  u16* __restrict__ o0, u16* __restrict__ o1,
                                                  u16* __restrict__ o2, u16* __restrict__ o3) {
    __shared__ u16 As[256 * 64];   // 32 KB
    __shared__ u16 Bs[128 * 64];   // 16 KB
    const int K = DD;
    const int t = threadIdx.x;
    const int lane = t & 63, w = t >> 6;
    const int wr = w >> 1, wc = w & 1;
    const int m0 = blockIdx.y * 256, n0 = blockIdx.x * 128;
    const int fRow = lane & 15, fThr = lane >> 4;
    f32x4 acc[8][4] = {};
    const u16* Abase = A + (size_t)m0 * K;
    const u16* Bbase = Wt + (size_t)n0 * K;

    for (int k0 = 0; k0 < K; k0 += 64) {
        __syncthreads();
#pragma unroll
        for (int i = 0; i < 8; i++) {
            int c = t + 256 * i;
            int row = c >> 3;
            int col = ((c & 7) ^ (row & 7)) * 8;
            gload16(Abase + (size_t)row * K + k0 + col, (char*)As + (size_t)c * 16);
        }
#pragma unroll
        for (int i = 0; i < 4; i++) {
            int c = t + 256 * i;
            int row = c >> 3;
            int col = ((c & 7) ^ (row & 7)) * 8;
            gload16(Bbase + (size_t)row * K + k0 + col, (char*)Bs + (size_t)c * 16);
        }
        __syncthreads();
#pragma unroll
        for (int kk = 0; kk < 64; kk += 32) {
            const int cjW = (kk >> 3) + fThr;
            short8 af[8], bf[4];
#pragma unroll
            for (int i = 0; i < 8; i++) {
                int R = wr * 128 + i * 16 + fRow;
                af[i] = *(const short8*)&As[(R * 8 + (cjW ^ (R & 7))) * 8];
            }
#pragma unroll
            for (int g = 0; g < 4; g++) {
                int R = wc * 64 + g * 16 + fRow;
                bf[g] = *(const short8*)&Bs[(R * 8 + (cjW ^ (R & 7))) * 8];
            }
#pragma unroll
            for (int i = 0; i < 8; i++)
#pragma unroll
                for (int g = 0; g < 4; g++)
                    acc[i][g] = __builtin_amdgcn_mfma_f32_16x16x32_bf16(af[i], bf[g], acc[i][g], 0, 0, 0);
        }
    }
    const int chunk = (n0 + wc * 64) / DD;
    const float* bp = (chunk == 0) ? b0 : (chunk == 1) ? b1 : (chunk == 2) ? b2 : b3;
    u16* op = (chunk == 0) ? o0 : (chunk == 1) ? o1 : (chunk == 2) ? o2 : o3;
    const int cb = n0 + wc * 64 - chunk * DD;
    if (chunk == 2) {
        // V written transposed vT[c][node]
#pragma unroll
        for (int g = 0; g < 4; g++) {
            int col = cb + g * 16 + fRow;
            float bv = bp[col];
#pragma unroll
            for (int i = 0; i < 8; i++) {
                int rowb = m0 + wr * 128 + i * 16 + fThr * 4;
                ushort4 st;
                st.x = f2b(acc[i][g][0] + bv);
                st.y = f2b(acc[i][g][1] + bv);
                st.z = f2b(acc[i][g][2] + bv);
                st.w = f2b(acc[i][g][3] + bv);
                *(ushort4*)(op + (size_t)col * NN + rowb) = st;
            }
        }
    } else {
#pragma unroll
        for (int g = 0; g < 4; g++) {
            int col = cb + g * 16 + fRow;
            float bv = bp[col];
#pragma unroll
            for (int i = 0; i < 8; i++) {
                int rowb = m0 + wr * 128 + i * 16 + fThr * 4;
#pragma unroll
                for (int rr = 0; rr < 4; rr++)
                    op[(size_t)(rowb + rr) * DD + col] = f2b(acc[i][g][rr] + bv);
            }
        }
    }
}

// ---------------- XC GEMM (128x128) + inline Aq + fused score reduction ----------------
__global__ __launch_bounds__(256) void gemm_xc(const u16* __restrict__ A,
                                               const u16* __restrict__ Wt,
                                               const u16* __restrict__ wt8,
                                               const float* __restrict__ atti_b,
                                               const float* __restrict__ atts_w,
                                               float* __restrict__ score) {
    __shared__ u16 As[128 * 64];
    __shared__ u16 Bs[128 * 64];
    __shared__ float aq_p[2][128];
    const int K = DD;
    const int t = threadIdx.x;
    const int lane = t & 63, w = t >> 6;
    const int wr = w >> 1, wc = w & 1;
    const int n0 = blockIdx.x * 128, m0 = blockIdx.y * 128;
    const int fRow = lane & 15, fThr = lane >> 4;

    {
        int col = t & 127, kh = t >> 7;
        const u16* xr = A + (size_t)m0 * DD + kh * 384;
        const u16* wr8 = wt8 + (size_t)(n0 + col) * DD + kh * 384;
        float s = 0.f;
#pragma unroll 8
        for (int j = 0; j < 96; j++) {
            ushort4 a4 = *(const ushort4*)(xr + j * 4);
            ushort4 b4 = *(const ushort4*)(wr8 + j * 4);
            s += b2f(a4.x) * b2f(b4.x) + b2f(a4.y) * b2f(b4.y)
               + b2f(a4.z) * b2f(b4.z) + b2f(a4.w) * b2f(b4.w);
        }
        aq_p[kh][col] = s;
    }

    f32x4 acc[4][4] = {};
    const u16* Abase = A + (size_t)m0 * K;
    const u16* Bbase = Wt + (size_t)n0 * K;
    for (int k0 = 0; k0 < K; k0 += 64) {
        __syncthreads();
#pragma unroll
        for (int i = 0; i < 4; i++) {
            int c = t + 256 * i;
            int row = c >> 3;
            int col = ((c & 7) ^ (row & 7)) * 8;
            gload16(Abase + (size_t)row * K + k0 + col, (char*)As + (size_t)c * 16);
            gload16(Bbase + (size_t)row * K + k0 + col, (char*)Bs + (size_t)c * 16);
        }
        __syncthreads();
#pragma unroll
        for (int kk = 0; kk < 64; kk += 32) {
            const int cjW = (kk >> 3) + fThr;
            short8 af[4], bf[4];
#pragma unroll
            for (int i = 0; i < 4; i++) {
                int R = wr * 64 + i * 16 + fRow;
                af[i] = *(const short8*)&As[(R * 8 + (cjW ^ (R & 7))) * 8];
            }
#pragma unroll
            for (int g = 0; g < 4; g++) {
                int R = wc * 64 + g * 16 + fRow;
                bf[g] = *(const short8*)&Bs[(R * 8 + (cjW ^ (R & 7))) * 8];
            }
#pragma unroll
            for (int i = 0; i < 4; i++)
#pragma unroll
                for (int g = 0; g < 4; g++)
                    acc[i][g] = __builtin_amdgcn_mfma_f32_16x16x32_bf16(af[i], bf[g], acc[i][g], 0, 0, 0);
        }
    }
    float rsum[4][4] = {};
#pragma unroll
    for (int g = 0; g < 4; g++) {
        int cl = wc * 64 + g * 16 + fRow;
        int col = n0 + cl;
        float bv = atti_b[col] + aq_p[0][cl] + aq_p[1][cl];
        float av = atts_w[col];
#pragma unroll
        for (int i = 0; i < 4; i++)
#pragma unroll
            for (int rr = 0; rr < 4; rr++) {
                float v = fmaxf(acc[i][g][rr] + bv, 0.f);
                rsum[i][rr] += v * av;
            }
    }
#pragma unroll
    for (int i = 0; i < 4; i++)
#pragma unroll
        for (int rr = 0; rr < 4; rr++) {
            float s = rsum[i][rr];
            s += __shfl_xor(s, 1, 16); s += __shfl_xor(s, 2, 16);
            s += __shfl_xor(s, 4, 16); s += __shfl_xor(s, 8, 16);
            if (fRow == 0)
                atomicAdd(&score[m0 + wr * 64 + i * 16 + fThr * 4 + rr], s);
        }
}

// ---------------- fused dense attention — DIRECT-GLOBAL fragments, 1 barrier ----------------
// All MFMA operands except P read straight from global (16B contiguous per lane, L2/L3
// resident). LDS = Pl only (17 KB). QK loop has NO barriers -> compiler pipelines via vmcnt.
__global__ __launch_bounds__(256) void attn_fused(const u16* __restrict__ qb,
                                                  const u16* __restrict__ kb,
                                                  const u16* __restrict__ vT,
                                                  const u8* __restrict__ cnt,
                                                  const u16* __restrict__ hs,
                                                  u16* __restrict__ out) {
    __shared__ u16 Pl[64][136];
    const int half = blockIdx.x, hd = blockIdx.y, g = blockIdx.z;
    const int t = threadIdx.x;
    const int lane = t & 63, w = t >> 6;
    const int fRow = lane & 15, fThr = lane >> 4;
    const int dstBase = g * 128 + half * 64;
    // A-fragment: Q row (dstBase + w*16+fRow), k = kk + fThr*8
    const u16* Qrow = qb + (size_t)(dstBase + w * 16 + fRow) * DD + hd * CCh + fThr * 8;
    // B-fragment: K row (g*128 + j*16+fRow), k = kk + fThr*8
    const u16* Krow = kb + (size_t)(g * 128 + fRow) * DD + hd * CCh + fThr * 8;

    // ---- QK^T: 12 iters x (1+8) direct 16B loads + 8 MFMAs, no barriers ----
    f32x4 acc[8] = {};
    for (int kk = 0; kk < CCh; kk += 32) {
        short8 af = *(const short8*)(Qrow + kk);
#pragma unroll
        for (int j = 0; j < 8; j++) {
            short8 bf = *(const short8*)(Krow + (size_t)(j * 16) * DD + kk);
            acc[j] = __builtin_amdgcn_mfma_f32_16x16x32_bf16(af, bf, acc[j], 0, 0, 0);
        }
    }

    // ---- masked count-weighted softmax (wave w owns rows w*16..+15) ----
    const float scale = 0.05103103630798288f;  // 1/sqrt(384)
    const u8* cg = cnt + ((size_t)g << 14);
    const int rbase = half * 64 + w * 16 + fThr * 4;
    float pv[8][4];
#pragma unroll
    for (int i = 0; i < 4; i++) {
        float m = -3.4e38f;
#pragma unroll
        for (int j = 0; j < 8; j++) {
            float c = (float)cg[(rbase + i) * 128 + j * 16 + fRow];
            float s = acc[j][i] * scale;
            pv[j][i] = c;
            if (c > 0.f) m = fmaxf(m, s);
        }
#pragma unroll
        for (int msk = 1; msk <= 8; msk <<= 1) m = fmaxf(m, __shfl_xor(m, msk, 16));
        float sum = 0.f;
#pragma unroll
        for (int j = 0; j < 8; j++) {
            float p = (pv[j][i] > 0.f) ? pv[j][i] * __expf(acc[j][i] * scale - m) : 0.f;
            pv[j][i] = p; sum += p;
        }
#pragma unroll
        for (int msk = 1; msk <= 8; msk <<= 1) sum += __shfl_xor(sum, msk, 16);
        float inv = (sum > 0.f) ? 1.f / sum : 0.f;
#pragma unroll
        for (int j = 0; j < 8; j++)
            Pl[w * 16 + fThr * 4 + i][j * 16 + fRow] = f2b(pv[j][i] * inv);
    }
    __syncthreads();   // the ONLY barrier: P C-layout -> A-layout via LDS

    // ---- PV: P from LDS (A), V^T direct from global (B), 6 channel chunks ----
    const u16* Vrow = vT + (size_t)(hd * CCh + fRow) * NN + g * 128 + fThr * 8;
    for (int cc = 0; cc < 6; cc++) {
        f32x4 acc2[4] = {};
#pragma unroll
        for (int kk = 0; kk < 128; kk += 32) {
            short8 af = *(const short8*)&Pl[w * 16 + fRow][kk + fThr * 8];
#pragma unroll
            for (int j = 0; j < 4; j++) {
                short8 bf = *(const short8*)(Vrow + (size_t)(cc * 64 + j * 16) * NN + kk);
                acc2[j] = __builtin_amdgcn_mfma_f32_16x16x32_bf16(af, bf, acc2[j], 0, 0, 0);
            }
        }
#pragma unroll
        for (int j = 0; j < 4; j++) {
            int c = hd * CCh + cc * 64 + j * 16 + fRow;
#pragma unroll
            for (int i = 0; i < 4; i++) {
                int row = dstBase + w * 16 + fThr * 4 + i;
                size_t idx = (size_t)row * DD + c;
                float r = fmaxf(acc2[j][i] + b2f(hs[idx]), 0.f);
                out[idx] = f2b(r);
            }
        }
    }
}

// ---------------- tail: score-softmax + pool + fc1(tanh) + fc2 + log_softmax ----------------
__global__ __launch_bounds__(256) void tail_kernel(const float* __restrict__ score,
                                                   const u16* __restrict__ hx,
                                                   const u16* __restrict__ wtfc1,
                                                   const float* __restrict__ fc1b,
                                                   const float* __restrict__ fc2w,
                                                   const float* __restrict__ fc2b,
                                                   float* __restrict__ outp) {
    int b = blockIdx.x, t = threadIdx.x;
    __shared__ float sprob[LLn];
    __shared__ u16 psh[DD];
    __shared__ float su[DD];
    __shared__ float sred[4][3];
    if (t < 64) {
        float s0 = score[b * LLn + t];
        float s1 = score[b * LLn + 64 + t];
        float mx = fmaxf(s0, s1);
#pragma unroll
        for (int m = 1; m <= 32; m <<= 1) mx = fmaxf(mx, __shfl_xor(mx, m, 64));
        float e0 = __expf(s0 - mx), e1 = __expf(s1 - mx);
        float sum = e0 + e1;
#pragma unroll
        for (int m = 1; m <= 32; m <<= 1) sum += __shfl_xor(sum, m, 64);
        float inv = 1.f / sum;
        sprob[t] = e0 * inv; sprob[t + 64] = e1 * inv;
    }
    __syncthreads();
    if (t < 192) {
        int c = t * 4;
        float a0 = 0, a1 = 0, a2 = 0, a3 = 0;
        for (int l = 0; l < LLn; l++) {
            float wl = sprob[l];
            ushort4 hv = *(const ushort4*)(hx + (size_t)(b * LLn + l) * DD + c);
            a0 += wl * b2f(hv.x); a1 += wl * b2f(hv.y); a2 += wl * b2f(hv.z); a3 += wl * b2f(hv.w);
        }
        ushort4 o; o.x = f2b(a0); o.y = f2b(a1); o.z = f2b(a2); o.w = f2b(a3);
        *(ushort4*)(psh + c) = o;
    }
    __syncthreads();
#pragma unroll
    for (int jj = 0; jj < 3; jj++) {
        int j = t + jj * 256;
        float s = fc1b[j];
        const u16* wrow = wtfc1 + (size_t)j * DD;
#pragma unroll 8
        for (int k = 0; k < DD; k += 4) {
            ushort4 w4 = *(const ushort4*)(wrow + k);
            ushort4 p4 = *(const ushort4*)(psh + k);
            s += b2f(p4.x) * b2f(w4.x) + b2f(p4.y) * b2f(w4.y)
               + b2f(p4.z) * b2f(w4.z) + b2f(p4.w) * b2f(w4.w);
        }
        su[j] = tanhf(s);
    }
    __syncthreads();
    float p0 = 0, p1 = 0, p2 = 0;
    for (int k = t; k < DD; k += 256) {
        float uv = su[k];
        p0 += uv * fc2w[k * 3 + 0]; p1 += uv * fc2w[k * 3 + 1]; p2 += uv * fc2w[k * 3 + 2];
    }
#pragma unroll
    for (int m = 1; m <= 32; m <<= 1) {
        p0 += __shfl_xor(p0, m, 64); p1 += __shfl_xor(p1, m, 64); p2 += __shfl_xor(p2, m, 64);
    }
    int w = t >> 6, lane = t & 63;
    if (lane == 0) { sred[w][0] = p0; sred[w][1] = p1; sred[w][2] = p2; }
    __syncthreads();
    if (t == 0) {
        float z0 = fc2b[0], z1 = fc2b[1], z2 = fc2b[2];
        for (int i = 0; i < 4; i++) { z0 += sred[i][0]; z1 += sred[i][1]; z2 += sred[i][2]; }
        float mx = fmaxf(z0, fmaxf(z1, z2));
        float lse = mx + logf(__expf(z0 - mx) + __expf(z1 - mx) + __expf(z2 - mx));
        outp[b * 3 + 0] = z0 - lse; outp[b * 3 + 1] = z1 - lse; outp[b * 3 + 2] = z2 - lse;
    }
}

// ---------------- launch ----------------
static inline char* carve(char*& p, size_t bytes) {
    char* r = p;
    p += (bytes + 255) & ~(size_t)255;
    return r;
}

extern "C" void kernel_launch(void* const* d_in, const int* in_sizes, int n_in,
                              void* d_out, int out_size, void* d_ws, size_t ws_size,
                              hipStream_t stream) {
    const float* x = (const float*)d_in[0];
    const int* ei = (const int*)d_in[1];
    const int* srcp = ei;
    const int* dstp = ei + EE;
    const float* wL[8] = {(const float*)d_in[2], (const float*)d_in[4], (const float*)d_in[6],
                          (const float*)d_in[8], (const float*)d_in[10], (const float*)d_in[12],
                          (const float*)d_in[14], (const float*)d_in[16]};
    const float* bL[8] = {(const float*)d_in[3], (const float*)d_in[5], (const float*)d_in[7],
                          (const float*)d_in[9], (const float*)d_in[11], (const float*)d_in[13],
                          (const float*)d_in[15], (const float*)d_in[17]};
    const float* atti_w = (const float*)d_in[18];
    const float* atti_b = (const float*)d_in[19];
    const float* atts_w = (const float*)d_in[20];
    const float* fc1_w = (const float*)d_in[22];
    const float* fc1_b = (const float*)d_in[23];
    const float* fc2_w = (const float*)d_in[24];
    const float* fc2_b = (const float*)d_in[25];
    float* outp = (float*)d_out;

    char* p = (char*)d_ws;
    const size_t ndb = (size_t)NN * DD * 2;
    const size_t wsz = (size_t)DD * DD * 2;
    u16* qb = (u16*)carve(p, ndb);
    u16* kb = (u16*)carve(p, ndb);
    u16* vt = (u16*)carve(p, ndb);   // V transposed [768][8192]
    u16* xb = (u16*)carve(p, ndb);   // layer1 input; reused as layer2 attn output (hp)
    u16* hb = (u16*)carve(p, ndb);   // layer1 attn output
    u16* hs = (u16*)carve(p, ndb);   // skip bf16
    u16* wtcat1 = (u16*)carve(p, wsz * 4);
    u16* wtcat2 = (u16*)carve(p, wsz * 4);
    u16* wt8 = (u16*)carve(p, wsz);
    u16* wt9 = (u16*)carve(p, wsz);
    u16* wtfc1 = (u16*)carve(p, wsz);
    u8* cnt = (u8*)carve(p, (size_t)BBg * 128 * 128);
    float* score = (float*)carve(p, NN * 4);

    // 1) prep: zero cnt/score + convert x -> bf16
    prep_kernel<<<6144, 256, 0, stream>>>(x, xb, (unsigned int*)cnt, score);

    // 2) combo: 11 transposes + cnt histogram
    TP11 tps;
    for (int i = 0; i < 4; i++) tps.a[i] = {wL[i], wtcat1 + (size_t)i * DD * DD, 0};
    for (int i = 0; i < 4; i++) tps.a[4 + i] = {wL[4 + i], wtcat2 + (size_t)i * DD * DD, 0};
    tps.a[8] = {atti_w, wt8, 0};
    tps.a[9] = {atti_w, wt9, DD};
    tps.a[10] = {fc1_w, wtfc1, 0};
    combo_kernel<<<dim3(144, 1, 12), 256, 0, stream>>>(tps, srcp, dstp, (unsigned int*)cnt);

    dim3 gf(24, 32);           // QKVS: N=3072/128, M=8192/256
    dim3 ga(2, 2, BBg);        // attention: (dst-half, head, graph)
    // 3-4) layer 1
    gemm256<<<gf, 256, 0, stream>>>(xb, wtcat1, bL[0], bL[1], bL[2], bL[3], qb, kb, vt, hs);
    attn_fused<<<ga, 256, 0, stream>>>(qb, kb, vt, cnt, hs, hb);
    // 5-6) layer 2
    gemm256<<<gf, 256, 0, stream>>>(hb, wtcat2, bL[4], bL[5], bL[6], bL[7], qb, kb, vt, hs);
    attn_fused<<<ga, 256, 0, stream>>>(qb, kb, vt, cnt, hs, xb);   // xb = hp bf16

    // 7) pooling scores: XC with inline Aq + fused score reduction
    gemm_xc<<<dim3(6, 64), 256, 0, stream>>>(xb, wt9, wt8, atti_b, atts_w, score);

    // 8) tail: softmax-pool + fc1 + fc2 + log_softmax
    tail_kernel<<<BBg, 256, 0, stream>>>(score, xb, wtfc1, fc1_b, fc2_w, fc2_b, outp);
}

// Round 10
// 350.175 us; speedup vs baseline: 1.0996x; 1.0996x over previous
//
#include <hip/hip_runtime.h>

#define NN 8192
#define DD 768
#define EE 131072
#define BBg 64
#define LLn 128
#define CCh 384

typedef unsigned short u16;
typedef unsigned char u8;
typedef __attribute__((ext_vector_type(8))) short short8;
typedef __attribute__((ext_vector_type(4))) float f32x4;

__device__ __forceinline__ float b2f(u16 u) {
    union { unsigned int i; float f; } x; x.i = ((unsigned int)u) << 16; return x.f;
}
__device__ __forceinline__ u16 f2b(float f) {
    union { float f; unsigned int i; } x; x.f = f;
    unsigned int r = x.i + 0x7fffu + ((x.i >> 16) & 1u);
    return (u16)(r >> 16);
}
__device__ __forceinline__ void gload16(const void* g, void* l) {
    __builtin_amdgcn_global_load_lds((const __attribute__((address_space(1))) void*)g,
                                     (__attribute__((address_space(3))) void*)l, 16, 0, 0);
}

// ---------------- prep: zero cnt + zero score + f32->bf16 convert (1 dispatch) ----------------
__global__ __launch_bounds__(256) void prep_kernel(const float* __restrict__ in,
                                                   u16* __restrict__ out,
                                                   unsigned int* __restrict__ cnt32,
                                                   float* __restrict__ score) {
    int i = blockIdx.x * 256 + threadIdx.x;   // grid 6144 blocks: i < NN*DD/4
    float4 v = ((const float4*)in)[i];
    ushort4 o; o.x = f2b(v.x); o.y = f2b(v.y); o.z = f2b(v.z); o.w = f2b(v.w);
    ((ushort4*)out)[i] = o;
    if (blockIdx.x < 1024) cnt32[i] = 0;                       // 1 MB cnt
    else if (blockIdx.x < 1056) score[i - 1024 * 256] = 0.f;   // 8192 floats
}

// ---------------- combo: weight transposes (z<11) + edge histogram (z=11) ----------------
struct TP { const float* src; u16* dst; int rowOff; };
struct TP11 { TP a[11]; };

__global__ __launch_bounds__(256) void combo_kernel(TP11 args,
                                                    const int* __restrict__ srcp,
                                                    const int* __restrict__ dstp,
                                                    unsigned int* __restrict__ cnt32) {
    __shared__ float tile[64][65];
    if (blockIdx.z == 11) {
        for (int e = blockIdx.x * 256 + threadIdx.x; e < EE; e += 144 * 256) {
            int d = dstp[e], s = srcp[e];
            int g = d >> 7;
            int idx = (g << 14) + ((d & 127) << 7) + (s & 127);
            atomicAdd(&cnt32[idx >> 2], 1u << ((idx & 3) * 8));
        }
        return;
    }
    TP tp = args.a[blockIdx.z];
    int bx = blockIdx.x % 12, by = blockIdx.x / 12;
    int n0 = bx * 64, k0 = by * 64;
    int t = threadIdx.x;
    int tc = t & 63, tr = t >> 6;
#pragma unroll
    for (int i = 0; i < 16; i++)
        tile[tr + i * 4][tc] = tp.src[(size_t)(tp.rowOff + k0 + tr + i * 4) * DD + n0 + tc];
    __syncthreads();
#pragma unroll
    for (int i = 0; i < 16; i++) {
        int row = tr + i * 4;
        tp.dst[(size_t)(n0 + row) * DD + k0 + tc] = f2b(tile[tc][row]);
    }
}

// ---------------- small GEMM (64x64 tile), for M=64 fc1 ----------------
enum { EPI_F32 = 1, EPI_TANH = 3 };

__global__ __launch_bounds__(256) void gemm_bf16(const u16* __restrict__ A,
                                                 const u16* __restrict__ Wt,
                                                 const float* __restrict__ bias,
                                                 void* __restrict__ outp, int K, int mode) {
    __shared__ u16 As[64][72];
    __shared__ u16 Bs[64][72];
    const int m0 = blockIdx.y * 64, n0 = blockIdx.x * 64;
    const int t = threadIdx.x;
    const int lane = t & 63, w = t >> 6;
    const int tr = t >> 2, tc = (t & 3) * 16;
    f32x4 acc[4] = {{0,0,0,0},{0,0,0,0},{0,0,0,0},{0,0,0,0}};
    const int fRow = lane & 15;
    const int fK = (lane >> 4) * 8;

    for (int k0 = 0; k0 < K; k0 += 64) {
        int4 a0 = *(const int4*)(A + (size_t)(m0 + tr) * K + k0 + tc);
        int4 a1 = *(const int4*)(A + (size_t)(m0 + tr) * K + k0 + tc + 8);
        int4 b0 = *(const int4*)(Wt + (size_t)(n0 + tr) * K + k0 + tc);
        int4 b1 = *(const int4*)(Wt + (size_t)(n0 + tr) * K + k0 + tc + 8);
        __syncthreads();
        *(int4*)&As[tr][tc] = a0; *(int4*)&As[tr][tc + 8] = a1;
        *(int4*)&Bs[tr][tc] = b0; *(int4*)&Bs[tr][tc + 8] = b1;
        __syncthreads();
#pragma unroll
        for (int s = 0; s < 2; s++) {
            short8 af = *(const short8*)&As[w * 16 + fRow][s * 32 + fK];
#pragma unroll
            for (int g = 0; g < 4; g++) {
                short8 bf = *(const short8*)&Bs[g * 16 + fRow][s * 32 + fK];
                acc[g] = __builtin_amdgcn_mfma_f32_16x16x32_bf16(af, bf, acc[g], 0, 0, 0);
            }
        }
    }
    const int colLocal = lane & 15;
    const int rowLocal = (lane >> 4) * 4;
#pragma unroll
    for (int g = 0; g < 4; g++) {
        int col = n0 + g * 16 + colLocal;
        float bv = bias ? bias[col] : 0.f;
#pragma unroll
        for (int i = 0; i < 4; i++) {
            int row = m0 + w * 16 + rowLocal + i;
            float v = acc[g][i] + bv;
            if (mode == EPI_TANH) v = tanhf(v);
            ((float*)outp)[(size_t)row * DD + col] = v;
        }
    }
}

// ---------------- QKVS GEMM: 256x128 tile, swizzled LDS, global_load_lds w16 ----------------
__global__ __launch_bounds__(256, 2) void gemm256(const u16* __restrict__ A,
                                                  const u16* __restrict__ Wt,
                                                  const float* __restrict__ b0,
                                                  const float* __restrict__ b1,
                                                  const float* __restrict__ b2,
                                                  const float* __restrict__ b3,
                                                  u16* __restrict__ o0, u16* __restrict__ o1,
                                                  u16* __restrict__ o2, u16* __restrict__ o3) {
    __shared__ u16 As[256 * 64];   // 32 KB
    __shared__ u16 Bs[128 * 64];   // 16 KB
    const int K = DD;
    const int t = threadIdx.x;
    const int lane = t & 63, w = t >> 6;
    const int wr = w >> 1, wc = w & 1;
    const int m0 = blockIdx.y * 256, n0 = blockIdx.x * 128;
    const int fRow = lane & 15, fThr = lane >> 4;
    f32x4 acc[8][4] = {};
    const u16* Abase = A + (size_t)m0 * K;
    const u16* Bbase = Wt + (size_t)n0 * K;

    for (int k0 = 0; k0 < K; k0 += 64) {
        __syncthreads();
#pragma unroll
        for (int i = 0; i < 8; i++) {
            int c = t + 256 * i;
            int row = c >> 3;
            int col = ((c & 7) ^ (row & 7)) * 8;
            gload16(Abase + (size_t)row * K + k0 + col, (char*)As + (size_t)c * 16);
        }
#pragma unroll
        for (int i = 0; i < 4; i++) {
            int c = t + 256 * i;
            int row = c >> 3;
            int col = ((c & 7) ^ (row & 7)) * 8;
            gload16(Bbase + (size_t)row * K + k0 + col, (char*)Bs + (size_t)c * 16);
        }
        __syncthreads();
#pragma unroll
        for (int kk = 0; kk < 64; kk += 32) {
            const int cjW = (kk >> 3) + fThr;
            short8 af[8], bf[4];
#pragma unroll
            for (int i = 0; i < 8; i++) {
                int R = wr * 128 + i * 16 + fRow;
                af[i] = *(const short8*)&As[(R * 8 + (cjW ^ (R & 7))) * 8];
            }
#pragma unroll
            for (int g = 0; g < 4; g++) {
                int R = wc * 64 + g * 16 + fRow;
                bf[g] = *(const short8*)&Bs[(R * 8 + (cjW ^ (R & 7))) * 8];
            }
#pragma unroll
            for (int i = 0; i < 8; i++)
#pragma unroll
                for (int g = 0; g < 4; g++)
                    acc[i][g] = __builtin_amdgcn_mfma_f32_16x16x32_bf16(af[i], bf[g], acc[i][g], 0, 0, 0);
        }
    }
    const int chunk = (n0 + wc * 64) / DD;
    const float* bp = (chunk == 0) ? b0 : (chunk == 1) ? b1 : (chunk == 2) ? b2 : b3;
    u16* op = (chunk == 0) ? o0 : (chunk == 1) ? o1 : (chunk == 2) ? o2 : o3;
    const int cb = n0 + wc * 64 - chunk * DD;
    if (chunk == 2) {
        // V written transposed vT[c][node]
#pragma unroll
        for (int g = 0; g < 4; g++) {
            int col = cb + g * 16 + fRow;
            float bv = bp[col];
#pragma unroll
            for (int i = 0; i < 8; i++) {
                int rowb = m0 + wr * 128 + i * 16 + fThr * 4;
                ushort4 st;
                st.x = f2b(acc[i][g][0] + bv);
                st.y = f2b(acc[i][g][1] + bv);
                st.z = f2b(acc[i][g][2] + bv);
                st.w = f2b(acc[i][g][3] + bv);
                *(ushort4*)(op + (size_t)col * NN + rowb) = st;
            }
        }
    } else {
#pragma unroll
        for (int g = 0; g < 4; g++) {
            int col = cb + g * 16 + fRow;
            float bv = bp[col];
#pragma unroll
            for (int i = 0; i < 8; i++) {
                int rowb = m0 + wr * 128 + i * 16 + fThr * 4;
#pragma unroll
                for (int rr = 0; rr < 4; rr++)
                    op[(size_t)(rowb + rr) * DD + col] = f2b(acc[i][g][rr] + bv);
            }
        }
    }
}

// ---------------- XC GEMM (128x128) + inline Aq + fused score reduction ----------------
__global__ __launch_bounds__(256) void gemm_xc(const u16* __restrict__ A,
                                               const u16* __restrict__ Wt,
                                               const u16* __restrict__ wt8,
                                               const float* __restrict__ atti_b,
                                               const float* __restrict__ atts_w,
                                               float* __restrict__ score) {
    __shared__ u16 As[128 * 64];
    __shared__ u16 Bs[128 * 64];
    __shared__ float aq_p[2][128];
    const int K = DD;
    const int t = threadIdx.x;
    const int lane = t & 63, w = t >> 6;
    const int wr = w >> 1, wc = w & 1;
    const int n0 = blockIdx.x * 128, m0 = blockIdx.y * 128;
    const int fRow = lane & 15, fThr = lane >> 4;

    {
        int col = t & 127, kh = t >> 7;
        const u16* xr = A + (size_t)m0 * DD + kh * 384;
        const u16* wr8 = wt8 + (size_t)(n0 + col) * DD + kh * 384;
        float s = 0.f;
#pragma unroll 8
        for (int j = 0; j < 96; j++) {
            ushort4 a4 = *(const ushort4*)(xr + j * 4);
            ushort4 b4 = *(const ushort4*)(wr8 + j * 4);
            s += b2f(a4.x) * b2f(b4.x) + b2f(a4.y) * b2f(b4.y)
               + b2f(a4.z) * b2f(b4.z) + b2f(a4.w) * b2f(b4.w);
        }
        aq_p[kh][col] = s;
    }

    f32x4 acc[4][4] = {};
    const u16* Abase = A + (size_t)m0 * K;
    const u16* Bbase = Wt + (size_t)n0 * K;
    for (int k0 = 0; k0 < K; k0 += 64) {
        __syncthreads();
#pragma unroll
        for (int i = 0; i < 4; i++) {
            int c = t + 256 * i;
            int row = c >> 3;
            int col = ((c & 7) ^ (row & 7)) * 8;
            gload16(Abase + (size_t)row * K + k0 + col, (char*)As + (size_t)c * 16);
            gload16(Bbase + (size_t)row * K + k0 + col, (char*)Bs + (size_t)c * 16);
        }
        __syncthreads();
#pragma unroll
        for (int kk = 0; kk < 64; kk += 32) {
            const int cjW = (kk >> 3) + fThr;
            short8 af[4], bf[4];
#pragma unroll
            for (int i = 0; i < 4; i++) {
                int R = wr * 64 + i * 16 + fRow;
                af[i] = *(const short8*)&As[(R * 8 + (cjW ^ (R & 7))) * 8];
            }
#pragma unroll
            for (int g = 0; g < 4; g++) {
                int R = wc * 64 + g * 16 + fRow;
                bf[g] = *(const short8*)&Bs[(R * 8 + (cjW ^ (R & 7))) * 8];
            }
#pragma unroll
            for (int i = 0; i < 4; i++)
#pragma unroll
                for (int g = 0; g < 4; g++)
                    acc[i][g] = __builtin_amdgcn_mfma_f32_16x16x32_bf16(af[i], bf[g], acc[i][g], 0, 0, 0);
        }
    }
    float rsum[4][4] = {};
#pragma unroll
    for (int g = 0; g < 4; g++) {
        int cl = wc * 64 + g * 16 + fRow;
        int col = n0 + cl;
        float bv = atti_b[col] + aq_p[0][cl] + aq_p[1][cl];
        float av = atts_w[col];
#pragma unroll
        for (int i = 0; i < 4; i++)
#pragma unroll
            for (int rr = 0; rr < 4; rr++) {
                float v = fmaxf(acc[i][g][rr] + bv, 0.f);
                rsum[i][rr] += v * av;
            }
    }
#pragma unroll
    for (int i = 0; i < 4; i++)
#pragma unroll
        for (int rr = 0; rr < 4; rr++) {
            float s = rsum[i][rr];
            s += __shfl_xor(s, 1, 16); s += __shfl_xor(s, 2, 16);
            s += __shfl_xor(s, 4, 16); s += __shfl_xor(s, 8, 16);
            if (fRow == 0)
                atomicAdd(&score[m0 + wr * 64 + i * 16 + fThr * 4 + rr], s);
        }
}

// ---------------- fused dense attention (R5 structure — best measured) ----------------
__global__ __launch_bounds__(256) void attn_fused(const u16* __restrict__ qb,
                                                  const u16* __restrict__ kb,
                                                  const u16* __restrict__ vT,
                                                  const u8* __restrict__ cnt,
                                                  const u16* __restrict__ hs,
                                                  u16* __restrict__ out) {
    __shared__ u16 As[64][72];
    __shared__ u16 Bs[128][72];
    __shared__ u16 Pl[64][136];
    __shared__ u16 Vt[64][136];
    const int half = blockIdx.x, hd = blockIdx.y, g = blockIdx.z;
    const int t = threadIdx.x;
    const int lane = t & 63, w = t >> 6;
    const int fRow = lane & 15, fThr = lane >> 4;
    const int dstBase = g * 128 + half * 64;
    const u16* Qb = qb + (size_t)dstBase * DD + hd * CCh;
    const u16* Kb = kb + (size_t)(g * 128) * DD + hd * CCh;

    f32x4 acc[8] = {};
    const int trA = t >> 2, tcA = (t & 3) * 16;
    const int trB = t >> 1, tcB = (t & 1) * 32;
    for (int k0 = 0; k0 < CCh; k0 += 64) {
        int4 a0 = *(const int4*)(Qb + (size_t)trA * DD + k0 + tcA);
        int4 a1 = *(const int4*)(Qb + (size_t)trA * DD + k0 + tcA + 8);
        int4 b0 = *(const int4*)(Kb + (size_t)trB * DD + k0 + tcB);
        int4 b1 = *(const int4*)(Kb + (size_t)trB * DD + k0 + tcB + 8);
        int4 b2 = *(const int4*)(Kb + (size_t)trB * DD + k0 + tcB + 16);
        int4 b3 = *(const int4*)(Kb + (size_t)trB * DD + k0 + tcB + 24);
        __syncthreads();
        *(int4*)&As[trA][tcA] = a0; *(int4*)&As[trA][tcA + 8] = a1;
        *(int4*)&Bs[trB][tcB] = b0; *(int4*)&Bs[trB][tcB + 8] = b1;
        *(int4*)&Bs[trB][tcB + 16] = b2; *(int4*)&Bs[trB][tcB + 24] = b3;
        __syncthreads();
#pragma unroll
        for (int kk = 0; kk < 64; kk += 32) {
            short8 af = *(const short8*)&As[w * 16 + fRow][kk + fThr * 8];
#pragma unroll
            for (int j = 0; j < 8; j++) {
                short8 bf = *(const short8*)&Bs[j * 16 + fRow][kk + fThr * 8];
                acc[j] = __builtin_amdgcn_mfma_f32_16x16x32_bf16(af, bf, acc[j], 0, 0, 0);
            }
        }
    }

    const float scale = 0.05103103630798288f;  // 1/sqrt(384)
    const u8* cg = cnt + ((size_t)g << 14);
    const int rbase = half * 64 + w * 16 + fThr * 4;
    float pv[8][4];
#pragma unroll
    for (int i = 0; i < 4; i++) {
        float m = -3.4e38f;
#pragma unroll
        for (int j = 0; j < 8; j++) {
            float c = (float)cg[(rbase + i) * 128 + j * 16 + fRow];
            float s = acc[j][i] * scale;
            pv[j][i] = c;
            if (c > 0.f) m = fmaxf(m, s);
        }
#pragma unroll
        for (int msk = 1; msk <= 8; msk <<= 1) m = fmaxf(m, __shfl_xor(m, msk, 16));
        float sum = 0.f;
#pragma unroll
        for (int j = 0; j < 8; j++) {
            float p = (pv[j][i] > 0.f) ? pv[j][i] * __expf(acc[j][i] * scale - m) : 0.f;
            pv[j][i] = p; sum += p;
        }
#pragma unroll
        for (int msk = 1; msk <= 8; msk <<= 1) sum += __shfl_xor(sum, msk, 16);
        float inv = (sum > 0.f) ? 1.f / sum : 0.f;
#pragma unroll
        for (int j = 0; j < 8; j++)
            Pl[w * 16 + fThr * 4 + i][j * 16 + fRow] = f2b(pv[j][i] * inv);
    }

    for (int cc = 0; cc < 6; cc++) {
        __syncthreads();
#pragma unroll
        for (int ii = 0; ii < 4; ii++) {
            int q = t + 256 * ii;
            int row = q >> 4, col = (q & 15) * 8;
            *(int4*)&Vt[row][col] =
                *(const int4*)(vT + (size_t)(hd * CCh + cc * 64 + row) * NN + g * 128 + col);
        }
        __syncthreads();
        f32x4 acc2[4] = {};
#pragma unroll
        for (int kk = 0; kk < 128; kk += 32) {
            short8 af = *(const short8*)&Pl[w * 16 + fRow][kk + fThr * 8];
#pragma unroll
            for (int j = 0; j < 4; j++) {
                short8 bf = *(const short8*)&Vt[j * 16 + fRow][kk + fThr * 8];
                acc2[j] = __builtin_amdgcn_mfma_f32_16x16x32_bf16(af, bf, acc2[j], 0, 0, 0);
            }
        }
#pragma unroll
        for (int j = 0; j < 4; j++) {
            int c = hd * CCh + cc * 64 + j * 16 + fRow;
#pragma unroll
            for (int i = 0; i < 4; i++) {
                int row = dstBase + w * 16 + fThr * 4 + i;
                size_t idx = (size_t)row * DD + c;
                float r = fmaxf(acc2[j][i] + b2f(hs[idx]), 0.f);
                out[idx] = f2b(r);
            }
        }
    }
}

// ---------------- per-graph softmax + weighted pool -> bf16 ----------------
__global__ __launch_bounds__(192) void pool_kernel(const float* __restrict__ score,
                                                   const u16* __restrict__ hx,
                                                   u16* __restrict__ pb) {
    int b = blockIdx.x, t = threadIdx.x;
    __shared__ float sprob[LLn];
    if (t < 64) {
        float s0 = score[b * LLn + t];
        float s1 = score[b * LLn + 64 + t];
        float mx = fmaxf(s0, s1);
#pragma unroll
        for (int m = 1; m <= 32; m <<= 1) mx = fmaxf(mx, __shfl_xor(mx, m, 64));
        float e0 = __expf(s0 - mx), e1 = __expf(s1 - mx);
        float sum = e0 + e1;
#pragma unroll
        for (int m = 1; m <= 32; m <<= 1) sum += __shfl_xor(sum, m, 64);
        float inv = 1.f / sum;
        sprob[t] = e0 * inv; sprob[t + 64] = e1 * inv;
    }
    __syncthreads();
    int c = t * 4;
    float a0 = 0, a1 = 0, a2 = 0, a3 = 0;
    for (int l = 0; l < LLn; l++) {
        float wl = sprob[l];
        ushort4 hv = *(const ushort4*)(hx + (size_t)(b * LLn + l) * DD + c);
        a0 += wl * b2f(hv.x); a1 += wl * b2f(hv.y); a2 += wl * b2f(hv.z); a3 += wl * b2f(hv.w);
    }
    ushort4 o; o.x = f2b(a0); o.y = f2b(a1); o.z = f2b(a2); o.w = f2b(a3);
    *(ushort4*)(pb + (size_t)b * DD + c) = o;
}

// ---------------- head tail: fc2 + log_softmax ----------------
__global__ __launch_bounds__(256) void head2_kernel(const float* __restrict__ u,
                                                    const float* __restrict__ fc2w,
                                                    const float* __restrict__ fc2b,
                                                    float* __restrict__ outp) {
    int b = blockIdx.x, t = threadIdx.x;
    __shared__ float sred[4][3];
    float p0 = 0, p1 = 0, p2 = 0;
    for (int k = t; k < DD; k += 256) {
        float uv = u[(size_t)b * DD + k];
        p0 += uv * fc2w[k * 3 + 0]; p1 += uv * fc2w[k * 3 + 1]; p2 += uv * fc2w[k * 3 + 2];
    }
#pragma unroll
    for (int m = 1; m <= 32; m <<= 1) {
        p0 += __shfl_xor(p0, m, 64); p1 += __shfl_xor(p1, m, 64); p2 += __shfl_xor(p2, m, 64);
    }
    int w = t >> 6, lane = t & 63;
    if (lane == 0) { sred[w][0] = p0; sred[w][1] = p1; sred[w][2] = p2; }
    __syncthreads();
    if (t == 0) {
        float z0 = fc2b[0], z1 = fc2b[1], z2 = fc2b[2];
        for (int i = 0; i < 4; i++) { z0 += sred[i][0]; z1 += sred[i][1]; z2 += sred[i][2]; }
        float mx = fmaxf(z0, fmaxf(z1, z2));
        float lse = mx + logf(__expf(z0 - mx) + __expf(z1 - mx) + __expf(z2 - mx));
        outp[b * 3 + 0] = z0 - lse; outp[b * 3 + 1] = z1 - lse; outp[b * 3 + 2] = z2 - lse;
    }
}

// ---------------- launch ----------------
static inline char* carve(char*& p, size_t bytes) {
    char* r = p;
    p += (bytes + 255) & ~(size_t)255;
    return r;
}

extern "C" void kernel_launch(void* const* d_in, const int* in_sizes, int n_in,
                              void* d_out, int out_size, void* d_ws, size_t ws_size,
                              hipStream_t stream) {
    const float* x = (const float*)d_in[0];
    const int* ei = (const int*)d_in[1];
    const int* srcp = ei;
    const int* dstp = ei + EE;
    const float* wL[8] = {(const float*)d_in[2], (const float*)d_in[4], (const float*)d_in[6],
                          (const float*)d_in[8], (const float*)d_in[10], (const float*)d_in[12],
                          (const float*)d_in[14], (const float*)d_in[16]};
    const float* bL[8] = {(const float*)d_in[3], (const float*)d_in[5], (const float*)d_in[7],
                          (const float*)d_in[9], (const float*)d_in[11], (const float*)d_in[13],
                          (const float*)d_in[15], (const float*)d_in[17]};
    const float* atti_w = (const float*)d_in[18];
    const float* atti_b = (const float*)d_in[19];
    const float* atts_w = (const float*)d_in[20];
    const float* fc1_w = (const float*)d_in[22];
    const float* fc1_b = (const float*)d_in[23];
    const float* fc2_w = (const float*)d_in[24];
    const float* fc2_b = (const float*)d_in[25];
    float* outp = (float*)d_out;

    char* p = (char*)d_ws;
    const size_t ndb = (size_t)NN * DD * 2;
    const size_t wsz = (size_t)DD * DD * 2;
    u16* qb = (u16*)carve(p, ndb);
    u16* kb = (u16*)carve(p, ndb);
    u16* vt = (u16*)carve(p, ndb);   // V transposed [768][8192]
    u16* xb = (u16*)carve(p, ndb);   // layer1 input; reused as layer2 attn output (hp)
    u16* hb = (u16*)carve(p, ndb);   // layer1 attn output
    u16* hs = (u16*)carve(p, ndb);   // skip bf16
    u16* wtcat1 = (u16*)carve(p, wsz * 4);
    u16* wtcat2 = (u16*)carve(p, wsz * 4);
    u16* wt8 = (u16*)carve(p, wsz);
    u16* wt9 = (u16*)carve(p, wsz);
    u16* wtfc1 = (u16*)carve(p, wsz);
    u16* pb = (u16*)carve(p, (size_t)BBg * DD * 2);
    float* uu = (float*)carve(p, (size_t)BBg * DD * 4);
    u8* cnt = (u8*)carve(p, (size_t)BBg * 128 * 128);
    float* score = (float*)carve(p, NN * 4);

    // 1) prep: zero cnt/score + convert x -> bf16
    prep_kernel<<<6144, 256, 0, stream>>>(x, xb, (unsigned int*)cnt, score);

    // 2) combo: 11 transposes + cnt histogram
    TP11 tps;
    for (int i = 0; i < 4; i++) tps.a[i] = {wL[i], wtcat1 + (size_t)i * DD * DD, 0};
    for (int i = 0; i < 4; i++) tps.a[4 + i] = {wL[4 + i], wtcat2 + (size_t)i * DD * DD, 0};
    tps.a[8] = {atti_w, wt8, 0};
    tps.a[9] = {atti_w, wt9, DD};
    tps.a[10] = {fc1_w, wtfc1, 0};
    combo_kernel<<<dim3(144, 1, 12), 256, 0, stream>>>(tps, srcp, dstp, (unsigned int*)cnt);

    dim3 gf(24, 32);           // QKVS: N=3072/128, M=8192/256
    dim3 ga(2, 2, BBg);        // attention: (dst-half, head, graph)
    // 3-4) layer 1
    gemm256<<<gf, 256, 0, stream>>>(xb, wtcat1, bL[0], bL[1], bL[2], bL[3], qb, kb, vt, hs);
    attn_fused<<<ga, 256, 0, stream>>>(qb, kb, vt, cnt, hs, hb);
    // 5-6) layer 2
    gemm256<<<gf, 256, 0, stream>>>(hb, wtcat2, bL[4], bL[5], bL[6], bL[7], qb, kb, vt, hs);
    attn_fused<<<ga, 256, 0, stream>>>(qb, kb, vt, cnt, hs, xb);   // xb = hp bf16

    // 7) pooling scores: XC with inline Aq + fused score reduction
    gemm_xc<<<dim3(6, 64), 256, 0, stream>>>(xb, wt9, wt8, atti_b, atts_w, score);

    // 8-10) R5 tail: pool -> bf16, fc1 MFMA gemm (tanh), fc2+log_softmax
    pool_kernel<<<BBg, 192, 0, stream>>>(score, xb, pb);
    gemm_bf16<<<dim3(12, 1), 256, 0, stream>>>(pb, wtfc1, fc1_b, uu, DD, EPI_TANH);
    head2_kernel<<<BBg, 256, 0, stream>>>(uu, fc2_w, fc2_b, outp);
}

// Round 11
// 344.876 us; speedup vs baseline: 1.1165x; 1.0154x over previous
//
#include <hip/hip_runtime.h>

#define NN 8192
#define DD 768
#define EE 131072
#define BBg 64
#define LLn 128
#define CCh 384

typedef unsigned short u16;
typedef unsigned char u8;
typedef __attribute__((ext_vector_type(8))) short short8;
typedef __attribute__((ext_vector_type(4))) float f32x4;

__device__ __forceinline__ float b2f(u16 u) {
    union { unsigned int i; float f; } x; x.i = ((unsigned int)u) << 16; return x.f;
}
__device__ __forceinline__ u16 f2b(float f) {
    union { float f; unsigned int i; } x; x.f = f;
    unsigned int r = x.i + 0x7fffu + ((x.i >> 16) & 1u);
    return (u16)(r >> 16);
}
__device__ __forceinline__ void gload16(const void* g, void* l) {
    __builtin_amdgcn_global_load_lds((const __attribute__((address_space(1))) void*)g,
                                     (__attribute__((address_space(3))) void*)l, 16, 0, 0);
}

// ---------------- prep: zero cnt + zero score + f32->bf16 convert (1 dispatch) ----------------
__global__ __launch_bounds__(256) void prep_kernel(const float* __restrict__ in,
                                                   u16* __restrict__ out,
                                                   unsigned int* __restrict__ cnt32,
                                                   float* __restrict__ score) {
    int i = blockIdx.x * 256 + threadIdx.x;   // grid 6144 blocks: i < NN*DD/4
    float4 v = ((const float4*)in)[i];
    ushort4 o; o.x = f2b(v.x); o.y = f2b(v.y); o.z = f2b(v.z); o.w = f2b(v.w);
    ((ushort4*)out)[i] = o;
    if (blockIdx.x < 1024) cnt32[i] = 0;                       // 1 MB cnt
    else if (blockIdx.x < 1056) score[i - 1024 * 256] = 0.f;   // 8192 floats
}

// ---------------- combo: weight transposes (z<11) + edge histogram (z=11) ----------------
struct TP { const float* src; u16* dst; int rowOff; };
struct TP11 { TP a[11]; };

__global__ __launch_bounds__(256) void combo_kernel(TP11 args,
                                                    const int* __restrict__ srcp,
                                                    const int* __restrict__ dstp,
                                                    unsigned int* __restrict__ cnt32) {
    __shared__ float tile[64][65];
    if (blockIdx.z == 11) {
        for (int e = blockIdx.x * 256 + threadIdx.x; e < EE; e += 144 * 256) {
            int d = dstp[e], s = srcp[e];
            int g = d >> 7;
            int idx = (g << 14) + ((d & 127) << 7) + (s & 127);
            atomicAdd(&cnt32[idx >> 2], 1u << ((idx & 3) * 8));
        }
        return;
    }
    TP tp = args.a[blockIdx.z];
    int bx = blockIdx.x % 12, by = blockIdx.x / 12;
    int n0 = bx * 64, k0 = by * 64;
    int t = threadIdx.x;
    int tc = t & 63, tr = t >> 6;
#pragma unroll
    for (int i = 0; i < 16; i++)
        tile[tr + i * 4][tc] = tp.src[(size_t)(tp.rowOff + k0 + tr + i * 4) * DD + n0 + tc];
    __syncthreads();
#pragma unroll
    for (int i = 0; i < 16; i++) {
        int row = tr + i * 4;
        tp.dst[(size_t)(n0 + row) * DD + k0 + tc] = f2b(tile[tc][row]);
    }
}

// ---------------- small GEMM (64x64 tile), for M=64 fc1 ----------------
enum { EPI_F32 = 1, EPI_TANH = 3 };

__global__ __launch_bounds__(256) void gemm_bf16(const u16* __restrict__ A,
                                                 const u16* __restrict__ Wt,
                                                 const float* __restrict__ bias,
                                                 void* __restrict__ outp, int K, int mode) {
    __shared__ u16 As[64][72];
    __shared__ u16 Bs[64][72];
    const int m0 = blockIdx.y * 64, n0 = blockIdx.x * 64;
    const int t = threadIdx.x;
    const int lane = t & 63, w = t >> 6;
    const int tr = t >> 2, tc = (t & 3) * 16;
    f32x4 acc[4] = {{0,0,0,0},{0,0,0,0},{0,0,0,0},{0,0,0,0}};
    const int fRow = lane & 15;
    const int fK = (lane >> 4) * 8;

    for (int k0 = 0; k0 < K; k0 += 64) {
        int4 a0 = *(const int4*)(A + (size_t)(m0 + tr) * K + k0 + tc);
        int4 a1 = *(const int4*)(A + (size_t)(m0 + tr) * K + k0 + tc + 8);
        int4 b0 = *(const int4*)(Wt + (size_t)(n0 + tr) * K + k0 + tc);
        int4 b1 = *(const int4*)(Wt + (size_t)(n0 + tr) * K + k0 + tc + 8);
        __syncthreads();
        *(int4*)&As[tr][tc] = a0; *(int4*)&As[tr][tc + 8] = a1;
        *(int4*)&Bs[tr][tc] = b0; *(int4*)&Bs[tr][tc + 8] = b1;
        __syncthreads();
#pragma unroll
        for (int s = 0; s < 2; s++) {
            short8 af = *(const short8*)&As[w * 16 + fRow][s * 32 + fK];
#pragma unroll
            for (int g = 0; g < 4; g++) {
                short8 bf = *(const short8*)&Bs[g * 16 + fRow][s * 32 + fK];
                acc[g] = __builtin_amdgcn_mfma_f32_16x16x32_bf16(af, bf, acc[g], 0, 0, 0);
            }
        }
    }
    const int colLocal = lane & 15;
    const int rowLocal = (lane >> 4) * 4;
#pragma unroll
    for (int g = 0; g < 4; g++) {
        int col = n0 + g * 16 + colLocal;
        float bv = bias ? bias[col] : 0.f;
#pragma unroll
        for (int i = 0; i < 4; i++) {
            int row = m0 + w * 16 + rowLocal + i;
            float v = acc[g][i] + bv;
            if (mode == EPI_TANH) v = tanhf(v);
            ((float*)outp)[(size_t)row * DD + col] = v;
        }
    }
}

// ---------------- QKVS GEMM: 256x128 tile + LDS-staged coalesced epilogue ----------------
__global__ __launch_bounds__(256, 2) void gemm256(const u16* __restrict__ A,
                                                  const u16* __restrict__ Wt,
                                                  const float* __restrict__ b0,
                                                  const float* __restrict__ b1,
                                                  const float* __restrict__ b2,
                                                  const float* __restrict__ b3,
                                                  u16* __restrict__ o0, u16* __restrict__ o1,
                                                  u16* __restrict__ o2, u16* __restrict__ o3) {
    __shared__ u16 smem[256 * 64 + 128 * 64];   // 48 KB: As | Bs, reused by epilogue staging
    u16* As = smem;
    u16* Bs = smem + 256 * 64;
    const int K = DD;
    const int t = threadIdx.x;
    const int lane = t & 63, w = t >> 6;
    const int wr = w >> 1, wc = w & 1;
    const int m0 = blockIdx.y * 256, n0 = blockIdx.x * 128;
    const int fRow = lane & 15, fThr = lane >> 4;
    f32x4 acc[8][4] = {};
    const u16* Abase = A + (size_t)m0 * K;
    const u16* Bbase = Wt + (size_t)n0 * K;

    for (int k0 = 0; k0 < K; k0 += 64) {
        __syncthreads();
#pragma unroll
        for (int i = 0; i < 8; i++) {
            int c = t + 256 * i;
            int row = c >> 3;
            int col = ((c & 7) ^ (row & 7)) * 8;
            gload16(Abase + (size_t)row * K + k0 + col, (char*)As + (size_t)c * 16);
        }
#pragma unroll
        for (int i = 0; i < 4; i++) {
            int c = t + 256 * i;
            int row = c >> 3;
            int col = ((c & 7) ^ (row & 7)) * 8;
            gload16(Bbase + (size_t)row * K + k0 + col, (char*)Bs + (size_t)c * 16);
        }
        __syncthreads();
#pragma unroll
        for (int kk = 0; kk < 64; kk += 32) {
            const int cjW = (kk >> 3) + fThr;
            short8 af[8], bf[4];
#pragma unroll
            for (int i = 0; i < 8; i++) {
                int R = wr * 128 + i * 16 + fRow;
                af[i] = *(const short8*)&As[(R * 8 + (cjW ^ (R & 7))) * 8];
            }
#pragma unroll
            for (int g = 0; g < 4; g++) {
                int R = wc * 64 + g * 16 + fRow;
                bf[g] = *(const short8*)&Bs[(R * 8 + (cjW ^ (R & 7))) * 8];
            }
#pragma unroll
            for (int i = 0; i < 8; i++)
#pragma unroll
                for (int g = 0; g < 4; g++)
                    acc[i][g] = __builtin_amdgcn_mfma_f32_16x16x32_bf16(af[i], bf[g], acc[i][g], 0, 0, 0);
        }
    }
    // ---- epilogue: stage C through LDS -> fully coalesced ushort4 stores ----
    // 128-col tile never straddles a 768 boundary (768 = 6*128): one dest per block.
    const int chunk = n0 / DD;
    const float* bp = (chunk == 0) ? b0 : (chunk == 1) ? b1 : (chunk == 2) ? b2 : b3;
    u16* op = (chunk == 0) ? o0 : (chunk == 1) ? o1 : (chunk == 2) ? o2 : o3;
    const int cb0 = n0 - chunk * DD;
    if (chunk == 2) {
        // vT[col][node]: stage per wc-half (64 cols x 256 nodes), 512 B contiguous per col
        u16 (*Cs2)[264] = (u16(*)[264])smem;
#pragma unroll
        for (int p = 0; p < 2; p++) {
            __syncthreads();   // prior readers (k-loop / prev pass) done
            if (wc == p) {
#pragma unroll
                for (int g = 0; g < 4; g++) {
                    float bv = bp[cb0 + p * 64 + g * 16 + fRow];
#pragma unroll
                    for (int i = 0; i < 8; i++)
#pragma unroll
                        for (int rr = 0; rr < 4; rr++)
                            Cs2[g * 16 + fRow][wr * 128 + i * 16 + fThr * 4 + rr] =
                                f2b(acc[i][g][rr] + bv);
                }
            }
            __syncthreads();
#pragma unroll
            for (int ii = 0; ii < 16; ii++) {
                int c = t + 256 * ii;            // 4096 chunks: col = c>>6, 8B node-chunk
                int col = c >> 6, ch = c & 63;
                *(ushort4*)(op + (size_t)(cb0 + p * 64 + col) * NN + m0 + ch * 4) =
                    *(const ushort4*)&Cs2[col][ch * 4];
            }
        }
    } else {
        // row-major out[node][768]: stage per wr-half (128 rows x 128 cols), 256 B/row
        u16 (*Cs)[136] = (u16(*)[136])smem;
#pragma unroll
        for (int p = 0; p < 2; p++) {
            __syncthreads();
            if (wr == p) {
#pragma unroll
                for (int g = 0; g < 4; g++) {
                    float bv = bp[cb0 + wc * 64 + g * 16 + fRow];
#pragma unroll
                    for (int i = 0; i < 8; i++)
#pragma unroll
                        for (int rr = 0; rr < 4; rr++)
                            Cs[i * 16 + fThr * 4 + rr][wc * 64 + g * 16 + fRow] =
                                f2b(acc[i][g][rr] + bv);
                }
            }
            __syncthreads();
#pragma unroll
            for (int ii = 0; ii < 16; ii++) {
                int c = t + 256 * ii;            // 4096 chunks: row = c>>5, 8B col-chunk
                int row = c >> 5, ch = c & 31;
                *(ushort4*)(op + (size_t)(m0 + p * 128 + row) * DD + cb0 + ch * 4) =
                    *(const ushort4*)&Cs[row][ch * 4];
            }
        }
    }
}

// ---------------- XC GEMM (128x128) + inline Aq + fused score reduction ----------------
__global__ __launch_bounds__(256) void gemm_xc(const u16* __restrict__ A,
                                               const u16* __restrict__ Wt,
                                               const u16* __restrict__ wt8,
                                               const float* __restrict__ atti_b,
                                               const float* __restrict__ atts_w,
                                               float* __restrict__ score) {
    __shared__ u16 As[128 * 64];
    __shared__ u16 Bs[128 * 64];
    __shared__ float aq_p[2][128];
    const int K = DD;
    const int t = threadIdx.x;
    const int lane = t & 63, w = t >> 6;
    const int wr = w >> 1, wc = w & 1;
    const int n0 = blockIdx.x * 128, m0 = blockIdx.y * 128;
    const int fRow = lane & 15, fThr = lane >> 4;

    {
        int col = t & 127, kh = t >> 7;
        const u16* xr = A + (size_t)m0 * DD + kh * 384;
        const u16* wr8 = wt8 + (size_t)(n0 + col) * DD + kh * 384;
        float s = 0.f;
#pragma unroll 8
        for (int j = 0; j < 96; j++) {
            ushort4 a4 = *(const ushort4*)(xr + j * 4);
            ushort4 b4 = *(const ushort4*)(wr8 + j * 4);
            s += b2f(a4.x) * b2f(b4.x) + b2f(a4.y) * b2f(b4.y)
               + b2f(a4.z) * b2f(b4.z) + b2f(a4.w) * b2f(b4.w);
        }
        aq_p[kh][col] = s;
    }

    f32x4 acc[4][4] = {};
    const u16* Abase = A + (size_t)m0 * K;
    const u16* Bbase = Wt + (size_t)n0 * K;
    for (int k0 = 0; k0 < K; k0 += 64) {
        __syncthreads();
#pragma unroll
        for (int i = 0; i < 4; i++) {
            int c = t + 256 * i;
            int row = c >> 3;
            int col = ((c & 7) ^ (row & 7)) * 8;
            gload16(Abase + (size_t)row * K + k0 + col, (char*)As + (size_t)c * 16);
            gload16(Bbase + (size_t)row * K + k0 + col, (char*)Bs + (size_t)c * 16);
        }
        __syncthreads();
#pragma unroll
        for (int kk = 0; kk < 64; kk += 32) {
            const int cjW = (kk >> 3) + fThr;
            short8 af[4], bf[4];
#pragma unroll
            for (int i = 0; i < 4; i++) {
                int R = wr * 64 + i * 16 + fRow;
                af[i] = *(const short8*)&As[(R * 8 + (cjW ^ (R & 7))) * 8];
            }
#pragma unroll
            for (int g = 0; g < 4; g++) {
                int R = wc * 64 + g * 16 + fRow;
                bf[g] = *(const short8*)&Bs[(R * 8 + (cjW ^ (R & 7))) * 8];
            }
#pragma unroll
            for (int i = 0; i < 4; i++)
#pragma unroll
                for (int g = 0; g < 4; g++)
                    acc[i][g] = __builtin_amdgcn_mfma_f32_16x16x32_bf16(af[i], bf[g], acc[i][g], 0, 0, 0);
        }
    }
    float rsum[4][4] = {};
#pragma unroll
    for (int g = 0; g < 4; g++) {
        int cl = wc * 64 + g * 16 + fRow;
        int col = n0 + cl;
        float bv = atti_b[col] + aq_p[0][cl] + aq_p[1][cl];
        float av = atts_w[col];
#pragma unroll
        for (int i = 0; i < 4; i++)
#pragma unroll
            for (int rr = 0; rr < 4; rr++) {
                float v = fmaxf(acc[i][g][rr] + bv, 0.f);
                rsum[i][rr] += v * av;
            }
    }
#pragma unroll
    for (int i = 0; i < 4; i++)
#pragma unroll
        for (int rr = 0; rr < 4; rr++) {
            float s = rsum[i][rr];
            s += __shfl_xor(s, 1, 16); s += __shfl_xor(s, 2, 16);
            s += __shfl_xor(s, 4, 16); s += __shfl_xor(s, 8, 16);
            if (fRow == 0)
                atomicAdd(&score[m0 + wr * 64 + i * 16 + fThr * 4 + rr], s);
        }
}

// ---------------- fused dense attention (R5 structure — best measured) ----------------
__global__ __launch_bounds__(256) void attn_fused(const u16* __restrict__ qb,
                                                  const u16* __restrict__ kb,
                                                  const u16* __restrict__ vT,
                                                  const u8* __restrict__ cnt,
                                                  const u16* __restrict__ hs,
                                                  u16* __restrict__ out) {
    __shared__ u16 As[64][72];
    __shared__ u16 Bs[128][72];
    __shared__ u16 Pl[64][136];
    __shared__ u16 Vt[64][136];
    const int half = blockIdx.x, hd = blockIdx.y, g = blockIdx.z;
    const int t = threadIdx.x;
    const int lane = t & 63, w = t >> 6;
    const int fRow = lane & 15, fThr = lane >> 4;
    const int dstBase = g * 128 + half * 64;
    const u16* Qb = qb + (size_t)dstBase * DD + hd * CCh;
    const u16* Kb = kb + (size_t)(g * 128) * DD + hd * CCh;

    f32x4 acc[8] = {};
    const int trA = t >> 2, tcA = (t & 3) * 16;
    const int trB = t >> 1, tcB = (t & 1) * 32;
    for (int k0 = 0; k0 < CCh; k0 += 64) {
        int4 a0 = *(const int4*)(Qb + (size_t)trA * DD + k0 + tcA);
        int4 a1 = *(const int4*)(Qb + (size_t)trA * DD + k0 + tcA + 8);
        int4 b0 = *(const int4*)(Kb + (size_t)trB * DD + k0 + tcB);
        int4 b1 = *(const int4*)(Kb + (size_t)trB * DD + k0 + tcB + 8);
        int4 b2 = *(const int4*)(Kb + (size_t)trB * DD + k0 + tcB + 16);
        int4 b3 = *(const int4*)(Kb + (size_t)trB * DD + k0 + tcB + 24);
        __syncthreads();
        *(int4*)&As[trA][tcA] = a0; *(int4*)&As[trA][tcA + 8] = a1;
        *(int4*)&Bs[trB][tcB] = b0; *(int4*)&Bs[trB][tcB + 8] = b1;
        *(int4*)&Bs[trB][tcB + 16] = b2; *(int4*)&Bs[trB][tcB + 24] = b3;
        __syncthreads();
#pragma unroll
        for (int kk = 0; kk < 64; kk += 32) {
            short8 af = *(const short8*)&As[w * 16 + fRow][kk + fThr * 8];
#pragma unroll
            for (int j = 0; j < 8; j++) {
                short8 bf = *(const short8*)&Bs[j * 16 + fRow][kk + fThr * 8];
                acc[j] = __builtin_amdgcn_mfma_f32_16x16x32_bf16(af, bf, acc[j], 0, 0, 0);
            }
        }
    }

    const float scale = 0.05103103630798288f;  // 1/sqrt(384)
    const u8* cg = cnt + ((size_t)g << 14);
    const int rbase = half * 64 + w * 16 + fThr * 4;
    float pv[8][4];
#pragma unroll
    for (int i = 0; i < 4; i++) {
        float m = -3.4e38f;
#pragma unroll
        for (int j = 0; j < 8; j++) {
            float c = (float)cg[(rbase + i) * 128 + j * 16 + fRow];
            float s = acc[j][i] * scale;
            pv[j][i] = c;
            if (c > 0.f) m = fmaxf(m, s);
        }
#pragma unroll
        for (int msk = 1; msk <= 8; msk <<= 1) m = fmaxf(m, __shfl_xor(m, msk, 16));
        float sum = 0.f;
#pragma unroll
        for (int j = 0; j < 8; j++) {
            float p = (pv[j][i] > 0.f) ? pv[j][i] * __expf(acc[j][i] * scale - m) : 0.f;
            pv[j][i] = p; sum += p;
        }
#pragma unroll
        for (int msk = 1; msk <= 8; msk <<= 1) sum += __shfl_xor(sum, msk, 16);
        float inv = (sum > 0.f) ? 1.f / sum : 0.f;
#pragma unroll
        for (int j = 0; j < 8; j++)
            Pl[w * 16 + fThr * 4 + i][j * 16 + fRow] = f2b(pv[j][i] * inv);
    }

    for (int cc = 0; cc < 6; cc++) {
        __syncthreads();
#pragma unroll
        for (int ii = 0; ii < 4; ii++) {
            int q = t + 256 * ii;
            int row = q >> 4, col = (q & 15) * 8;
            *(int4*)&Vt[row][col] =
                *(const int4*)(vT + (size_t)(hd * CCh + cc * 64 + row) * NN + g * 128 + col);
        }
        __syncthreads();
        f32x4 acc2[4] = {};
#pragma unroll
        for (int kk = 0; kk < 128; kk += 32) {
            short8 af = *(const short8*)&Pl[w * 16 + fRow][kk + fThr * 8];
#pragma unroll
            for (int j = 0; j < 4; j++) {
                short8 bf = *(const short8*)&Vt[j * 16 + fRow][kk + fThr * 8];
                acc2[j] = __builtin_amdgcn_mfma_f32_16x16x32_bf16(af, bf, acc2[j], 0, 0, 0);
            }
        }
#pragma unroll
        for (int j = 0; j < 4; j++) {
            int c = hd * CCh + cc * 64 + j * 16 + fRow;
#pragma unroll
            for (int i = 0; i < 4; i++) {
                int row = dstBase + w * 16 + fThr * 4 + i;
                size_t idx = (size_t)row * DD + c;
                float r = fmaxf(acc2[j][i] + b2f(hs[idx]), 0.f);
                out[idx] = f2b(r);
            }
        }
    }
}

// ---------------- per-graph softmax + weighted pool -> bf16 ----------------
__global__ __launch_bounds__(192) void pool_kernel(const float* __restrict__ score,
                                                   const u16* __restrict__ hx,
                                                   u16* __restrict__ pb) {
    int b = blockIdx.x, t = threadIdx.x;
    __shared__ float sprob[LLn];
    if (t < 64) {
        float s0 = score[b * LLn + t];
        float s1 = score[b * LLn + 64 + t];
        float mx = fmaxf(s0, s1);
#pragma unroll
        for (int m = 1; m <= 32; m <<= 1) mx = fmaxf(mx, __shfl_xor(mx, m, 64));
        float e0 = __expf(s0 - mx), e1 = __expf(s1 - mx);
        float sum = e0 + e1;
#pragma unroll
        for (int m = 1; m <= 32; m <<= 1) sum += __shfl_xor(sum, m, 64);
        float inv = 1.f / sum;
        sprob[t] = e0 * inv; sprob[t + 64] = e1 * inv;
    }
    __syncthreads();
    int c = t * 4;
    float a0 = 0, a1 = 0, a2 = 0, a3 = 0;
    for (int l = 0; l < LLn; l++) {
        float wl = sprob[l];
        ushort4 hv = *(const ushort4*)(hx + (size_t)(b * LLn + l) * DD + c);
        a0 += wl * b2f(hv.x); a1 += wl * b2f(hv.y); a2 += wl * b2f(hv.z); a3 += wl * b2f(hv.w);
    }
    ushort4 o; o.x = f2b(a0); o.y = f2b(a1); o.z = f2b(a2); o.w = f2b(a3);
    *(ushort4*)(pb + (size_t)b * DD + c) = o;
}

// ---------------- head tail: fc2 + log_softmax ----------------
__global__ __launch_bounds__(256) void head2_kernel(const float* __restrict__ u,
                                                    const float* __restrict__ fc2w,
                                                    const float* __restrict__ fc2b,
                                                    float* __restrict__ outp) {
    int b = blockIdx.x, t = threadIdx.x;
    __shared__ float sred[4][3];
    float p0 = 0, p1 = 0, p2 = 0;
    for (int k = t; k < DD; k += 256) {
        float uv = u[(size_t)b * DD + k];
        p0 += uv * fc2w[k * 3 + 0]; p1 += uv * fc2w[k * 3 + 1]; p2 += uv * fc2w[k * 3 + 2];
    }
#pragma unroll
    for (int m = 1; m <= 32; m <<= 1) {
        p0 += __shfl_xor(p0, m, 64); p1 += __shfl_xor(p1, m, 64); p2 += __shfl_xor(p2, m, 64);
    }
    int w = t >> 6, lane = t & 63;
    if (lane == 0) { sred[w][0] = p0; sred[w][1] = p1; sred[w][2] = p2; }
    __syncthreads();
    if (t == 0) {
        float z0 = fc2b[0], z1 = fc2b[1], z2 = fc2b[2];
        for (int i = 0; i < 4; i++) { z0 += sred[i][0]; z1 += sred[i][1]; z2 += sred[i][2]; }
        float mx = fmaxf(z0, fmaxf(z1, z2));
        float lse = mx + logf(__expf(z0 - mx) + __expf(z1 - mx) + __expf(z2 - mx));
        outp[b * 3 + 0] = z0 - lse; outp[b * 3 + 1] = z1 - lse; outp[b * 3 + 2] = z2 - lse;
    }
}

// ---------------- launch ----------------
static inline char* carve(char*& p, size_t bytes) {
    char* r = p;
    p += (bytes + 255) & ~(size_t)255;
    return r;
}

extern "C" void kernel_launch(void* const* d_in, const int* in_sizes, int n_in,
                              void* d_out, int out_size, void* d_ws, size_t ws_size,
                              hipStream_t stream) {
    const float* x = (const float*)d_in[0];
    const int* ei = (const int*)d_in[1];
    const int* srcp = ei;
    const int* dstp = ei + EE;
    const float* wL[8] = {(const float*)d_in[2], (const float*)d_in[4], (const float*)d_in[6],
                          (const float*)d_in[8], (const float*)d_in[10], (const float*)d_in[12],
                          (const float*)d_in[14], (const float*)d_in[16]};
    const float* bL[8] = {(const float*)d_in[3], (const float*)d_in[5], (const float*)d_in[7],
                          (const float*)d_in[9], (const float*)d_in[11], (const float*)d_in[13],
                          (const float*)d_in[15], (const float*)d_in[17]};
    const float* atti_w = (const float*)d_in[18];
    const float* atti_b = (const float*)d_in[19];
    const float* atts_w = (const float*)d_in[20];
    const float* fc1_w = (const float*)d_in[22];
    const float* fc1_b = (const float*)d_in[23];
    const float* fc2_w = (const float*)d_in[24];
    const float* fc2_b = (const float*)d_in[25];
    float* outp = (float*)d_out;

    char* p = (char*)d_ws;
    const size_t ndb = (size_t)NN * DD * 2;
    const size_t wsz = (size_t)DD * DD * 2;
    u16* qb = (u16*)carve(p, ndb);
    u16* kb = (u16*)carve(p, ndb);
    u16* vt = (u16*)carve(p, ndb);   // V transposed [768][8192]
    u16* xb = (u16*)carve(p, ndb);   // layer1 input; reused as layer2 attn output (hp)
    u16* hb = (u16*)carve(p, ndb);   // layer1 attn output
    u16* hs = (u16*)carve(p, ndb);   // skip bf16
    u16* wtcat1 = (u16*)carve(p, wsz * 4);
    u16* wtcat2 = (u16*)carve(p, wsz * 4);
    u16* wt8 = (u16*)carve(p, wsz);
    u16* wt9 = (u16*)carve(p, wsz);
    u16* wtfc1 = (u16*)carve(p, wsz);
    u16* pb = (u16*)carve(p, (size_t)BBg * DD * 2);
    float* uu = (float*)carve(p, (size_t)BBg * DD * 4);
    u8* cnt = (u8*)carve(p, (size_t)BBg * 128 * 128);
    float* score = (float*)carve(p, NN * 4);

    // 1) prep: zero cnt/score + convert x -> bf16
    prep_kernel<<<6144, 256, 0, stream>>>(x, xb, (unsigned int*)cnt, score);

    // 2) combo: 11 transposes + cnt histogram
    TP11 tps;
    for (int i = 0; i < 4; i++) tps.a[i] = {wL[i], wtcat1 + (size_t)i * DD * DD, 0};
    for (int i = 0; i < 4; i++) tps.a[4 + i] = {wL[4 + i], wtcat2 + (size_t)i * DD * DD, 0};
    tps.a[8] = {atti_w, wt8, 0};
    tps.a[9] = {atti_w, wt9, DD};
    tps.a[10] = {fc1_w, wtfc1, 0};
    combo_kernel<<<dim3(144, 1, 12), 256, 0, stream>>>(tps, srcp, dstp, (unsigned int*)cnt);

    dim3 gf(24, 32);           // QKVS: N=3072/128, M=8192/256
    dim3 ga(2, 2, BBg);        // attention: (dst-half, head, graph)
    // 3-4) layer 1
    gemm256<<<gf, 256, 0, stream>>>(xb, wtcat1, bL[0], bL[1], bL[2], bL[3], qb, kb, vt, hs);
    attn_fused<<<ga, 256, 0, stream>>>(qb, kb, vt, cnt, hs, hb);
    // 5-6) layer 2
    gemm256<<<gf, 256, 0, stream>>>(hb, wtcat2, bL[4], bL[5], bL[6], bL[7], qb, kb, vt, hs);
    attn_fused<<<ga, 256, 0, stream>>>(qb, kb, vt, cnt, hs, xb);   // xb = hp bf16

    // 7) pooling scores: XC with inline Aq + fused score reduction
    gemm_xc<<<dim3(6, 64), 256, 0, stream>>>(xb, wt9, wt8, atti_b, atts_w, score);

    // 8-10) tail: pool -> bf16, fc1 MFMA gemm (tanh), fc2+log_softmax
    pool_kernel<<<BBg, 192, 0, stream>>>(score, xb, pb);
    gemm_bf16<<<dim3(12, 1), 256, 0, stream>>>(pb, wtfc1, fc1_b, uu, DD, EPI_TANH);
    head2_kernel<<<BBg, 256, 0, stream>>>(uu, fc2_w, fc2_b, outp);
}